// Round 3
// baseline (106414.319 us; speedup 1.0000x reference)
//
#include <hip/hip_runtime.h>

// ODE_Vanilla scan: B=128, T=256, I=256, H=1024, C=10, fp32 throughout.
//   phase1: v = a*h - relu(h@Wh + XW[t])   (XW = X@Wx + b precomputed)
//   phase2: u = v@Wh^T; grad = a*v - (phi>0)*u; h -= LR*grad; out[b,t,:]=h@fc_w+fc_b
// R5: persistent kernel (1024 blocks = 4/CU co-resident, T-loop in-kernel,
// 16 independent per-rt-group sense-reversing barriers over 64 blocks each;
// batch rows are independent so no full-grid sync) + value-splitting shfl
// reduce (30 swizzles vs 128 -> ~4x less DS-pipe reduction cost).

constexpr int Bsz = 128, Tn = 256, In = 256, Hn = 1024, Cn = 10;
constexpr float LR = 0.001f;
constexpr int HP = 1024 + 32;  // 8 chunks of 128, each padded +4 floats
#define HSW(k) ((k) + (((k) >> 7) << 2))  // swizzled LDS index

__global__ __launch_bounds__(256) void k_transpose(const float* __restrict__ W,
                                                   float* __restrict__ WT) {
  __shared__ float tile[32][33];
  const int bx = blockIdx.x * 32, by = blockIdx.y * 32;
  const int tx = threadIdx.x & 31, ty = threadIdx.x >> 5;
#pragma unroll
  for (int dy = 0; dy < 32; dy += 8)
    tile[ty + dy][tx] = W[(size_t)(by + ty + dy) * Hn + bx + tx];
  __syncthreads();
#pragma unroll
  for (int dy = 0; dy < 32; dy += 8)
    WT[(size_t)(bx + ty + dy) * Hn + by + tx] = tile[tx][ty + dy];
}

__global__ __launch_bounds__(256) void k_init(float* __restrict__ out,
                                              const float* __restrict__ fc_b,
                                              float* __restrict__ h_cur,
                                              const float* __restrict__ hidden,
                                              int* __restrict__ bar) {
  const int i = blockIdx.x * blockDim.x + threadIdx.x;
  if (i < Bsz * Tn * Cn) out[i] = fc_b[i % Cn];
  if (i < Bsz * Hn) h_cur[i] = hidden[i];
  if (i < 1024) bar[i] = 0;
}

__device__ __forceinline__ void fma4(float4& a, float s, const float4& w) {
  a.x = fmaf(s, w.x, a.x);
  a.y = fmaf(s, w.y, a.y);
  a.z = fmaf(s, w.z, a.z);
  a.w = fmaf(s, w.w, a.w);
}

__device__ __forceinline__ float4 shfl4(float4 v, int m) {
  v.x = __shfl_xor(v.x, m, 64);
  v.y = __shfl_xor(v.y, m, 64);
  v.z = __shfl_xor(v.z, m, 64);
  v.w = __shfl_xor(v.w, m, 64);
  return v;
}

__device__ __forceinline__ float4 add4(float4 a, float4 b) {
  return make_float4(a.x + b.x, a.y + b.y, a.z + b.z, a.w + b.w);
}

// XW[t][b][n] = sum_k X[b][t][k]*Wx[k][n] + bias[n].
__global__ __launch_bounds__(256) void k_xw(const float* __restrict__ X,
                                            const float* __restrict__ Wx,
                                            const float* __restrict__ bias,
                                            float* __restrict__ xw) {
  const int nt = blockIdx.x & 15, mt = blockIdx.x >> 4;
  const int t = mt >> 1, b0 = (mt & 1) * 64;
  const int cl = threadIdx.x & 15, rg = threadIdx.x >> 4;
  const int col = nt * 64 + cl * 4;
  const int row = b0 + rg * 4;
  float4 acc0 = {0, 0, 0, 0}, acc1 = {0, 0, 0, 0}, acc2 = {0, 0, 0, 0},
         acc3 = {0, 0, 0, 0};
  const size_t xstride = (size_t)Tn * In;
  const float* xp = X + ((size_t)row * Tn + t) * In;
  const float* wp = Wx + col;
#pragma unroll 2
  for (int k = 0; k < In; k += 4) {
    const float4 x0 = *(const float4*)(xp + k);
    const float4 x1 = *(const float4*)(xp + xstride + k);
    const float4 x2 = *(const float4*)(xp + 2 * xstride + k);
    const float4 x3 = *(const float4*)(xp + 3 * xstride + k);
    const float4 w0 = *(const float4*)(wp + (size_t)k * Hn);
    const float4 w1 = *(const float4*)(wp + (size_t)(k + 1) * Hn);
    const float4 w2 = *(const float4*)(wp + (size_t)(k + 2) * Hn);
    const float4 w3 = *(const float4*)(wp + (size_t)(k + 3) * Hn);
    fma4(acc0, x0.x, w0); fma4(acc0, x0.y, w1); fma4(acc0, x0.z, w2); fma4(acc0, x0.w, w3);
    fma4(acc1, x1.x, w0); fma4(acc1, x1.y, w1); fma4(acc1, x1.z, w2); fma4(acc1, x1.w, w3);
    fma4(acc2, x2.x, w0); fma4(acc2, x2.y, w1); fma4(acc2, x2.z, w2); fma4(acc2, x2.w, w3);
    fma4(acc3, x3.x, w0); fma4(acc3, x3.y, w1); fma4(acc3, x3.z, w2); fma4(acc3, x3.w, w3);
  }
  const float4 b4 = *(const float4*)(bias + col);
  float4 o[4] = {acc0, acc1, acc2, acc3};
#pragma unroll
  for (int i = 0; i < 4; i++) {
    float4 v = o[i];
    v.x += b4.x; v.y += b4.y; v.z += b4.z; v.w += b4.w;
    *(float4*)(xw + ((size_t)t * Bsz + row + i) * Hn + col) = v;
  }
}

// Per-rt-group (64 blocks) sense-reversing barrier. All blocks co-resident
// (grid 1024 = 4/CU exactly), so spinning is deadlock-free. Release:
// __threadfence (wbl2) after the implicit pre-barrier vmcnt drain; acquire:
// agent-scope atomic load (emits cache inv for cross-XCD visibility).
__device__ __forceinline__ void rt_barrier(int* cnt, int* gen) {
  __threadfence();
  __syncthreads();
  if (threadIdx.x == 0) {
    const int g = __hip_atomic_load(gen, __ATOMIC_RELAXED, __HIP_MEMORY_SCOPE_AGENT);
    const int old =
        __hip_atomic_fetch_add(cnt, 1, __ATOMIC_ACQ_REL, __HIP_MEMORY_SCOPE_AGENT);
    if (old == 63) {
      __hip_atomic_store(cnt, 0, __ATOMIC_RELAXED, __HIP_MEMORY_SCOPE_AGENT);
      __hip_atomic_fetch_add(gen, 1, __ATOMIC_RELEASE, __HIP_MEMORY_SCOPE_AGENT);
    } else {
      while (__hip_atomic_load(gen, __ATOMIC_ACQUIRE, __HIP_MEMORY_SCOPE_AGENT) == g)
        __builtin_amdgcn_s_sleep(2);
    }
  }
  __syncthreads();
}

// 8-rows x 16-cols x K=1024 panel GEMM inner loop (thread = c4 x kk(64)).
__device__ __forceinline__ void gemm8(const float (*s)[HP],
                                      const float* __restrict__ W, int kk,
                                      int col, float4 acc[8]) {
#pragma unroll
  for (int q = 0; q < 4; q++) {
    const int k = 4 * kk + 256 * q;
    const float* Wp = W + (size_t)k * Hn + col;
    const float4 w0 = *(const float4*)(Wp);
    const float4 w1 = *(const float4*)(Wp + Hn);
    const float4 w2 = *(const float4*)(Wp + 2 * Hn);
    const float4 w3 = *(const float4*)(Wp + 3 * Hn);
#pragma unroll
    for (int r = 0; r < 8; r++) {
      const float4 h4 = *(const float4*)(&s[r][HSW(k)]);
      fma4(acc[r], h4.x, w0);
      fma4(acc[r], h4.y, w1);
      fma4(acc[r], h4.z, w2);
      fma4(acc[r], h4.w, w3);
    }
  }
}

// Value-splitting reduce over ks (16 lanes/group): 30 shfl vs 128 full-width.
// Each lane ends owning rows r_own, cols (c_own, c_own+1); writes to part.
__device__ __forceinline__ void reduce_vs(float4 acc[8], int c4, int ksw,
                                          int wv, float (*part)[8][16]) {
  const bool u1 = ksw & 1;
#pragma unroll
  for (int i = 0; i < 4; i++) {
    const float4 snd = u1 ? acc[i] : acc[i + 4];
    const float4 kp = u1 ? acc[i + 4] : acc[i];
    acc[i] = add4(kp, shfl4(snd, 4));
  }
  const bool u2 = ksw & 2;
#pragma unroll
  for (int i = 0; i < 2; i++) {
    const float4 snd = u2 ? acc[i] : acc[i + 2];
    const float4 kp = u2 ? acc[i + 2] : acc[i];
    acc[i] = add4(kp, shfl4(snd, 8));
  }
  const bool u3 = ksw & 4;
  {
    const float4 snd = u3 ? acc[0] : acc[1];
    const float4 kp = u3 ? acc[1] : acc[0];
    acc[0] = add4(kp, shfl4(snd, 16));
  }
  const bool u4 = ksw & 8;
  float sx = u4 ? acc[0].x : acc[0].z;
  float sy = u4 ? acc[0].y : acc[0].w;
  const float kx = u4 ? acc[0].z : acc[0].x;
  const float ky = u4 ? acc[0].w : acc[0].y;
  sx = __shfl_xor(sx, 32, 64);
  sy = __shfl_xor(sy, 32, 64);
  const int r_own = ((ksw & 1) << 2) | (ksw & 2) | ((ksw >> 2) & 1);
  const int c_own = 4 * c4 + (u4 ? 2 : 0);
  *(float2*)&part[wv][r_own][c_own] = make_float2(kx + sx, ky + sy);
}

// Persistent scan kernel. grid 1024 = rt(16) x ct(64); 4 blocks/CU resident.
template <int PRE>
__global__ __launch_bounds__(256, 4) void k_scan(
    float* __restrict__ h, const float* __restrict__ X,
    const float* __restrict__ Wh, const float* __restrict__ WT,
    const float* __restrict__ Wx, const float* __restrict__ bias,
    const float* __restrict__ alpha, const float* __restrict__ xw,
    const float* __restrict__ fc_w, float* __restrict__ out,
    float* __restrict__ hfin, float* __restrict__ v_buf,
    int* __restrict__ bar) {
  __shared__ float s_rows[8][HP];       // 33 KB: staged h (phase1) / v (phase2)
  __shared__ float part[4][8][16];      // 2 KB: cross-wave partials
  __shared__ float hn_s[8][16];         // updated h tile for FC
  const int ct = blockIdx.x & 63, rt = blockIdx.x >> 6;
  const int c0 = ct * 16, r0 = rt * 8;
  const int tid = threadIdx.x;
  const int c4 = tid & 3, kk = tid >> 2;
  const int col = c0 + 4 * c4;
  const int wv = tid >> 6, ksw = (tid & 63) >> 2;
  const float av = alpha[0];
  int* bcnt = bar + rt * 32;
  int* bgen = bar + 512 + rt * 32;

#pragma unroll 1
  for (int t = 0; t < Tn; ++t) {
    // ---------- phase 1: v = a*h - relu(h@Wh + xw) ----------
    {
      const float4* src = (const float4*)(h + (size_t)r0 * Hn);
#pragma unroll
      for (int u = 0; u < 8; u++) {
        const int f = tid + 256 * u;
        const int row = f >> 8, k = (f & 255) * 4;
        *(float4*)&s_rows[row][HSW(k)] = src[f];
      }
    }
    __syncthreads();
    float4 acc[8];
#pragma unroll
    for (int r = 0; r < 8; r++) acc[r] = {0.f, 0.f, 0.f, 0.f};
    gemm8(s_rows, Wh, kk, col, acc);
    if (!PRE) {  // x@Wx inline: thread kk owns Wx row-quad 4kk (I=256=64*4)
      const int kx = 4 * kk;
      const float* Wp = Wx + (size_t)kx * Hn + col;
      const float4 w0 = *(const float4*)(Wp);
      const float4 w1 = *(const float4*)(Wp + Hn);
      const float4 w2 = *(const float4*)(Wp + 2 * Hn);
      const float4 w3 = *(const float4*)(Wp + 3 * Hn);
#pragma unroll
      for (int r = 0; r < 8; r++) {
        const float4 x4 =
            *(const float4*)(X + ((size_t)(r0 + r) * Tn + t) * In + kx);
        fma4(acc[r], x4.x, w0);
        fma4(acc[r], x4.y, w1);
        fma4(acc[r], x4.z, w2);
        fma4(acc[r], x4.w, w3);
      }
    }
    reduce_vs(acc, c4, ksw, wv, part);
    __syncthreads();
    if (tid < 128) {
      const int r = tid >> 4, c = tid & 15;
      const float u =
          part[0][r][c] + part[1][r][c] + part[2][r][c] + part[3][r][c];
      const float a1 = PRE ? xw[((size_t)t * Bsz + r0 + r) * Hn + c0 + c]
                           : bias[c0 + c];
      const float hv = s_rows[r][HSW(c0 + c)];
      v_buf[(size_t)(r0 + r) * Hn + c0 + c] = av * hv - fmaxf(u + a1, 0.f);
    }
    rt_barrier(bcnt, bgen);  // all 64 ct-blocks of rt: v complete

    // ---------- phase 2: u = v@Wh^T; h update; FC ----------
    {
      const float4* src = (const float4*)(v_buf + (size_t)r0 * Hn);
#pragma unroll
      for (int u = 0; u < 8; u++) {
        const int f = tid + 256 * u;
        const int row = f >> 8, k = (f & 255) * 4;
        *(float4*)&s_rows[row][HSW(k)] = src[f];
      }
    }
    __syncthreads();
#pragma unroll
    for (int r = 0; r < 8; r++) acc[r] = {0.f, 0.f, 0.f, 0.f};
    gemm8(s_rows, WT, kk, col, acc);
    reduce_vs(acc, c4, ksw, wv, part);
    __syncthreads();
    if (tid < 128) {
      const int r = tid >> 4, c = tid & 15;
      const float u =
          part[0][r][c] + part[1][r][c] + part[2][r][c] + part[3][r][c];
      const size_t hoff = (size_t)(r0 + r) * Hn + c0 + c;
      const float vv = s_rows[r][HSW(c0 + c)];
      const float hv = h[hoff];
      // phi = a*h - v; grad = a*v - (phi>0)*u; hn = h - LR*grad
      const float hn =
          hv - LR * (av * vv - ((av * hv - vv) > 0.f ? u : 0.f));
      h[hoff] = hn;
      if (t == Tn - 1) hfin[hoff] = hn;
      hn_s[r][c] = hn;
    }
    __syncthreads();
    if (tid < 80) {  // FC partial over this block's 16 cols -> 80 atomics
      const int rr = tid / 10, c = tid % 10;
      float s = 0.f;
#pragma unroll
      for (int jj = 0; jj < 16; jj++)
        s += hn_s[rr][jj] * fc_w[(size_t)(c0 + jj) * Cn + c];
      atomicAdd(&out[((size_t)(r0 + rr) * Tn + t) * Cn + c], s);
    }
    rt_barrier(bcnt, bgen);  // h fully updated before next step's staging
  }
}

extern "C" void kernel_launch(void* const* d_in, const int* in_sizes, int n_in,
                              void* d_out, int out_size, void* d_ws, size_t ws_size,
                              hipStream_t stream) {
  const float* X      = (const float*)d_in[0];
  const float* hidden = (const float*)d_in[1];
  const float* alpha  = (const float*)d_in[2];
  const float* bias   = (const float*)d_in[3];
  const float* Wh     = (const float*)d_in[4];
  const float* Wx     = (const float*)d_in[5];
  const float* fc_w   = (const float*)d_in[6];
  const float* fc_b   = (const float*)d_in[7];
  float* out  = (float*)d_out;
  float* hfin = out + (size_t)Bsz * Tn * Cn;

  char* ws = (char*)d_ws;
  float* WhT   = (float*)ws;                                   // 4 MB
  float* h_cur = WhT + (size_t)Hn * Hn;
  float* v_buf = h_cur + (size_t)Bsz * Hn;
  int*   bar   = (int*)(v_buf + (size_t)Bsz * Hn);             // 4 KB
  float* XW    = (float*)(bar + 1024);                         // 134 MB
  const size_t need_pre =
      ((size_t)Hn * Hn + 2 * (size_t)Bsz * Hn + (size_t)Bsz * Tn * Hn) *
          sizeof(float) +
      1024 * sizeof(int);
  const bool pre = ws_size >= need_pre;

  k_transpose<<<dim3(32, 32), 256, 0, stream>>>(Wh, WhT);
  k_init<<<(Bsz * Tn * Cn + 255) / 256, 256, 0, stream>>>(out, fc_b, h_cur,
                                                          hidden, bar);
  if (pre) k_xw<<<8192, 256, 0, stream>>>(X, Wx, bias, XW);
  if (pre)
    k_scan<1><<<1024, 256, 0, stream>>>(h_cur, X, Wh, WhT, Wx, bias, alpha, XW,
                                        fc_w, out, hfin, v_buf, bar);
  else
    k_scan<0><<<1024, 256, 0, stream>>>(h_cur, X, Wh, WhT, Wx, bias, alpha, XW,
                                        fc_w, out, hfin, v_buf, bar);
}

// Round 4
// 9283.270 us; speedup vs baseline: 11.4630x; 11.4630x over previous
//
#include <hip/hip_runtime.h>

// ODE_Vanilla scan: B=128, T=256, I=256, H=1024, C=10, fp32 throughout.
//   phase1: v = a*h - relu(h@Wh + XW[t])   (XW = X@Wx + b precomputed)
//   phase2: u = v@Wh^T; grad = a*v - (phi>0)*u; h -= LR*grad; out[b,t,:]=h@fc_w+fc_b
// R6: back to multi-launch (R5 persistent barriers cost 266us each — agent
// scope coherence nukes L2; launch boundary IS the cheap barrier). DS-pipe
// diet vs R4: thread tile 8 rows x 8 cols, K-split 128 (ds_reads 32->16),
// value-splitting butterfly (62 b32 shfl vs 128), linear LDS (contiguous
// lane addressing -> conflict-free, no swizzle math).

constexpr int Bsz = 128, Tn = 256, In = 256, Hn = 1024, Cn = 10;
constexpr float LR = 0.001f;

__global__ __launch_bounds__(256) void k_transpose(const float* __restrict__ W,
                                                   float* __restrict__ WT) {
  __shared__ float tile[32][33];
  const int bx = blockIdx.x * 32, by = blockIdx.y * 32;
  const int tx = threadIdx.x & 31, ty = threadIdx.x >> 5;
#pragma unroll
  for (int dy = 0; dy < 32; dy += 8)
    tile[ty + dy][tx] = W[(size_t)(by + ty + dy) * Hn + bx + tx];
  __syncthreads();
#pragma unroll
  for (int dy = 0; dy < 32; dy += 8)
    WT[(size_t)(bx + ty + dy) * Hn + by + tx] = tile[tx][ty + dy];
}

__global__ __launch_bounds__(256) void k_init(float* __restrict__ out,
                                              const float* __restrict__ fc_b,
                                              float* __restrict__ h_cur,
                                              const float* __restrict__ hidden) {
  const int i = blockIdx.x * blockDim.x + threadIdx.x;
  if (i < Bsz * Tn * Cn) out[i] = fc_b[i % Cn];
  if (i < Bsz * Hn) h_cur[i] = hidden[i];
}

__device__ __forceinline__ void fma4(float4& a, float s, const float4& w) {
  a.x = fmaf(s, w.x, a.x);
  a.y = fmaf(s, w.y, a.y);
  a.z = fmaf(s, w.z, a.z);
  a.w = fmaf(s, w.w, a.w);
}

__device__ __forceinline__ float4 shfl4(float4 v, int m) {
  v.x = __shfl_xor(v.x, m, 64);
  v.y = __shfl_xor(v.y, m, 64);
  v.z = __shfl_xor(v.z, m, 64);
  v.w = __shfl_xor(v.w, m, 64);
  return v;
}

__device__ __forceinline__ float4 add4(float4 a, float4 b) {
  return make_float4(a.x + b.x, a.y + b.y, a.z + b.z, a.w + b.w);
}

// XW[t][b][n] = sum_k X[b][t][k]*Wx[k][n] + bias[n].
__global__ __launch_bounds__(256) void k_xw(const float* __restrict__ X,
                                            const float* __restrict__ Wx,
                                            const float* __restrict__ bias,
                                            float* __restrict__ xw) {
  const int nt = blockIdx.x & 15, mt = blockIdx.x >> 4;
  const int t = mt >> 1, b0 = (mt & 1) * 64;
  const int cl = threadIdx.x & 15, rg = threadIdx.x >> 4;
  const int col = nt * 64 + cl * 4;
  const int row = b0 + rg * 4;
  float4 acc0 = {0, 0, 0, 0}, acc1 = {0, 0, 0, 0}, acc2 = {0, 0, 0, 0},
         acc3 = {0, 0, 0, 0};
  const size_t xstride = (size_t)Tn * In;
  const float* xp = X + ((size_t)row * Tn + t) * In;
  const float* wp = Wx + col;
#pragma unroll 2
  for (int k = 0; k < In; k += 4) {
    const float4 x0 = *(const float4*)(xp + k);
    const float4 x1 = *(const float4*)(xp + xstride + k);
    const float4 x2 = *(const float4*)(xp + 2 * xstride + k);
    const float4 x3 = *(const float4*)(xp + 3 * xstride + k);
    const float4 w0 = *(const float4*)(wp + (size_t)k * Hn);
    const float4 w1 = *(const float4*)(wp + (size_t)(k + 1) * Hn);
    const float4 w2 = *(const float4*)(wp + (size_t)(k + 2) * Hn);
    const float4 w3 = *(const float4*)(wp + (size_t)(k + 3) * Hn);
    fma4(acc0, x0.x, w0); fma4(acc0, x0.y, w1); fma4(acc0, x0.z, w2); fma4(acc0, x0.w, w3);
    fma4(acc1, x1.x, w0); fma4(acc1, x1.y, w1); fma4(acc1, x1.z, w2); fma4(acc1, x1.w, w3);
    fma4(acc2, x2.x, w0); fma4(acc2, x2.y, w1); fma4(acc2, x2.z, w2); fma4(acc2, x2.w, w3);
    fma4(acc3, x3.x, w0); fma4(acc3, x3.y, w1); fma4(acc3, x3.z, w2); fma4(acc3, x3.w, w3);
  }
  const float4 b4 = *(const float4*)(bias + col);
  float4 o[4] = {acc0, acc1, acc2, acc3};
#pragma unroll
  for (int i = 0; i < 4; i++) {
    float4 v = o[i];
    v.x += b4.x; v.y += b4.y; v.z += b4.z; v.w += b4.w;
    *(float4*)(xw + ((size_t)t * Bsz + row + i) * Hn + col) = v;
  }
}

// P[2r+j]: j=0 cols +0..3, j=1 cols +4..7, of colb = c0 + 8*c8.
// 8x8x(K=1024 split 128-way over ks): per q in {0,1}, k = 4*ks + 512*q.
__device__ __forceinline__ void gemm8x8(const float (*s)[Hn],
                                        const float* __restrict__ W, int ks,
                                        int colb, float4 P[16]) {
#pragma unroll
  for (int q = 0; q < 2; q++) {
    const int k = 4 * ks + 512 * q;
    float4 h4[8];
#pragma unroll
    for (int r = 0; r < 8; r++) h4[r] = *(const float4*)&s[r][k];
    const float* Wp = W + (size_t)k * Hn + colb;
#pragma unroll
    for (int i = 0; i < 4; i++) {
      const float4 wa = *(const float4*)(Wp);
      const float4 wb = *(const float4*)(Wp + 4);
      Wp += Hn;
#pragma unroll
      for (int r = 0; r < 8; r++) {
        const float hi = (i == 0)   ? h4[r].x
                         : (i == 1) ? h4[r].y
                         : (i == 2) ? h4[r].z
                                    : h4[r].w;
        fma4(P[2 * r], hi, wa);
        fma4(P[2 * r + 1], hi, wb);
      }
    }
  }
}

// Value-splitting butterfly over ks lane bits (1,2,4,8,16 -> masks 2..32):
// each stage gives away half the accumulators; 62 b32 shfl total. Lane ends
// owning float2 at (r_own, col 8c8+4u4+2u5); writes to part[wv].
__device__ __forceinline__ void reduce_vs8(float4 P[16], int ks, int c8,
                                           int wv, float (*part)[8][16]) {
  const bool u1 = ks & 1, u2 = ks & 2, u3 = ks & 4, u4 = ks & 8, u5 = ks & 16;
#pragma unroll
  for (int i = 0; i < 8; i++) {
    const float4 snd = u1 ? P[i] : P[i + 8];
    const float4 kp = u1 ? P[i + 8] : P[i];
    P[i] = add4(kp, shfl4(snd, 2));
  }
#pragma unroll
  for (int i = 0; i < 4; i++) {
    const float4 snd = u2 ? P[i] : P[i + 4];
    const float4 kp = u2 ? P[i + 4] : P[i];
    P[i] = add4(kp, shfl4(snd, 4));
  }
#pragma unroll
  for (int i = 0; i < 2; i++) {
    const float4 snd = u3 ? P[i] : P[i + 2];
    const float4 kp = u3 ? P[i + 2] : P[i];
    P[i] = add4(kp, shfl4(snd, 8));
  }
  {
    const float4 snd = u4 ? P[0] : P[1];
    const float4 kp = u4 ? P[1] : P[0];
    P[0] = add4(kp, shfl4(snd, 16));
  }
  float sx = u5 ? P[0].x : P[0].z;
  float sy = u5 ? P[0].y : P[0].w;
  const float kx = u5 ? P[0].z : P[0].x;
  const float ky = u5 ? P[0].w : P[0].y;
  sx = __shfl_xor(sx, 32, 64);
  sy = __shfl_xor(sy, 32, 64);
  const int r_own = (u1 ? 4 : 0) | (u2 ? 2 : 0) | (u3 ? 1 : 0);
  const int cl = 8 * c8 + (u4 ? 4 : 0) + (u5 ? 2 : 0);
  *(float2*)&part[wv][r_own][cl] = make_float2(kx + sx, ky + sy);
}

// grid 1024 = rt(16, 8 rows) x ct(64, 16 cols); thread = c8(2) x ks(128).
template <int PRE>
__global__ __launch_bounds__(256, 4) void k_phase1(
    const float* __restrict__ h, const float* __restrict__ X,
    const float* __restrict__ Wh, const float* __restrict__ Wx,
    const float* __restrict__ bias, const float* __restrict__ alpha,
    const float* __restrict__ xw, float* __restrict__ v_out, int t) {
  __shared__ float s_rows[8][Hn];       // 32 KB, linear
  __shared__ float part[4][8][16];      // 2 KB
  const int ct = blockIdx.x & 63, rt = blockIdx.x >> 6;
  const int c0 = ct * 16, r0 = rt * 8;
  const int tid = threadIdx.x;
  {  // stage 8 h rows (8192 contiguous floats)
    const float4* src = (const float4*)(h + (size_t)r0 * Hn);
#pragma unroll
    for (int u = 0; u < 8; u++) {
      const int f = tid + 256 * u;
      ((float4*)s_rows)[f] = src[f];
    }
  }
  __syncthreads();

  const int c8 = tid & 1, ks = tid >> 1, wv = tid >> 6;
  const int colb = c0 + 8 * c8;
  float4 P[16];
#pragma unroll
  for (int i = 0; i < 16; i++) P[i] = {0.f, 0.f, 0.f, 0.f};
  gemm8x8(s_rows, Wh, ks, colb, P);
  if (!PRE) {  // x@Wx inline: thread ks owns Wx rows {2ks, 2ks+1}
    const int kx = 2 * ks;
    const float* Wp = Wx + (size_t)kx * Hn + colb;
    const float4 wa0 = *(const float4*)(Wp);
    const float4 wb0 = *(const float4*)(Wp + 4);
    const float4 wa1 = *(const float4*)(Wp + Hn);
    const float4 wb1 = *(const float4*)(Wp + Hn + 4);
#pragma unroll
    for (int r = 0; r < 8; r++) {
      const float2 x2 =
          *(const float2*)(X + ((size_t)(r0 + r) * Tn + t) * In + kx);
      fma4(P[2 * r], x2.x, wa0);
      fma4(P[2 * r + 1], x2.x, wb0);
      fma4(P[2 * r], x2.y, wa1);
      fma4(P[2 * r + 1], x2.y, wb1);
    }
  }
  reduce_vs8(P, ks, c8, wv, part);
  __syncthreads();
  if (tid < 128) {
    const int r = tid >> 4, c = tid & 15;
    const float u =
        part[0][r][c] + part[1][r][c] + part[2][r][c] + part[3][r][c];
    const float a1 =
        PRE ? xw[((size_t)t * Bsz + r0 + r) * Hn + c0 + c] : bias[c0 + c];
    const float av = alpha[0];
    const float hv = s_rows[r][c0 + c];
    v_out[(size_t)(r0 + r) * Hn + c0 + c] = av * hv - fmaxf(u + a1, 0.f);
  }
}

__global__ __launch_bounds__(256, 4) void k_phase2(
    float* __restrict__ h, const float* __restrict__ v_in,
    const float* __restrict__ WT, const float* __restrict__ alpha,
    const float* __restrict__ fc_w, float* __restrict__ out,
    float* __restrict__ hfin, int t, int last) {
  __shared__ float s_rows[8][Hn];
  __shared__ float part[4][8][16];
  __shared__ float hn_s[8][16];
  const int ct = blockIdx.x & 63, rt = blockIdx.x >> 6;
  const int c0 = ct * 16, r0 = rt * 8;
  const int tid = threadIdx.x;
  {
    const float4* src = (const float4*)(v_in + (size_t)r0 * Hn);
#pragma unroll
    for (int u = 0; u < 8; u++) {
      const int f = tid + 256 * u;
      ((float4*)s_rows)[f] = src[f];
    }
  }
  __syncthreads();

  const int c8 = tid & 1, ks = tid >> 1, wv = tid >> 6;
  const int colb = c0 + 8 * c8;
  float4 P[16];
#pragma unroll
  for (int i = 0; i < 16; i++) P[i] = {0.f, 0.f, 0.f, 0.f};
  gemm8x8(s_rows, WT, ks, colb, P);
  reduce_vs8(P, ks, c8, wv, part);
  __syncthreads();
  if (tid < 128) {
    const int r = tid >> 4, c = tid & 15;
    const float u =
        part[0][r][c] + part[1][r][c] + part[2][r][c] + part[3][r][c];
    const float av = alpha[0];
    const size_t hoff = (size_t)(r0 + r) * Hn + c0 + c;
    const float vv = s_rows[r][c0 + c];
    const float hv = h[hoff];
    // phi = a*h - v; grad = a*v - (phi>0)*u; hn = h - LR*grad
    const float hn = hv - LR * (av * vv - ((av * hv - vv) > 0.f ? u : 0.f));
    h[hoff] = hn;
    if (last) hfin[hoff] = hn;
    hn_s[r][c] = hn;
  }
  __syncthreads();
  if (tid < 80) {  // FC partial over this block's 16 cols -> 80 atomics
    const int rr = tid / 10, c = tid % 10;
    float s = 0.f;
#pragma unroll
    for (int jj = 0; jj < 16; jj++)
      s += hn_s[rr][jj] * fc_w[(size_t)(c0 + jj) * Cn + c];
    atomicAdd(&out[((size_t)(r0 + rr) * Tn + t) * Cn + c], s);
  }
}

extern "C" void kernel_launch(void* const* d_in, const int* in_sizes, int n_in,
                              void* d_out, int out_size, void* d_ws, size_t ws_size,
                              hipStream_t stream) {
  const float* X      = (const float*)d_in[0];
  const float* hidden = (const float*)d_in[1];
  const float* alpha  = (const float*)d_in[2];
  const float* bias   = (const float*)d_in[3];
  const float* Wh     = (const float*)d_in[4];
  const float* Wx     = (const float*)d_in[5];
  const float* fc_w   = (const float*)d_in[6];
  const float* fc_b   = (const float*)d_in[7];
  float* out  = (float*)d_out;
  float* hfin = out + (size_t)Bsz * Tn * Cn;

  char* ws = (char*)d_ws;
  float* WhT   = (float*)ws;                        // 4 MB
  float* h_cur = WhT + (size_t)Hn * Hn;
  float* v_buf = h_cur + (size_t)Bsz * Hn;
  float* XW    = v_buf + (size_t)Bsz * Hn;          // 134 MB, [t][b][n]
  const size_t need =
      ((size_t)Hn * Hn + 2 * (size_t)Bsz * Hn + (size_t)Bsz * Tn * Hn) *
      sizeof(float);
  const bool pre = ws_size >= need;

  k_transpose<<<dim3(32, 32), 256, 0, stream>>>(Wh, WhT);
  k_init<<<(Bsz * Tn * Cn + 255) / 256, 256, 0, stream>>>(out, fc_b, h_cur,
                                                          hidden);
  if (pre) k_xw<<<8192, 256, 0, stream>>>(X, Wx, bias, XW);
  for (int t = 0; t < Tn; t++) {
    if (pre)
      k_phase1<1><<<1024, 256, 0, stream>>>(h_cur, X, Wh, Wx, bias, alpha, XW,
                                            v_buf, t);
    else
      k_phase1<0><<<1024, 256, 0, stream>>>(h_cur, X, Wh, Wx, bias, alpha, XW,
                                            v_buf, t);
    k_phase2<<<1024, 256, 0, stream>>>(h_cur, v_buf, WhT, alpha, fc_w, out,
                                       hfin, t, t == Tn - 1);
  }
}

// Round 5
// 6030.275 us; speedup vs baseline: 17.6467x; 1.5394x over previous
//
#include <hip/hip_runtime.h>

// ODE_Vanilla scan: B=128, T=256, I=256, H=1024, C=10, fp32 throughout.
//   phase1: v = a*h - relu(h@Wh + XW[t])   (XW = X@Wx + b precomputed)
//   phase2: u = v@Wh^T; grad = a*v - (phi>0)*u; h -= LR*grad; out[b,t,:]=h@fc_w+fc_b
// R7: R4's proven 4x4-tile gemm8 (acc=32 VGPR, no spills) + two DS-pipe cuts:
//  (1) no LDS staging — h/v read direct from global (L2-hot 32KB/block tile;
//      c4-lanes broadcast-merge), moving ~450cy/wave from DS to idle VMEM;
//  (2) R5's validated value-splitting butterfly (30 shfl vs 128).
// Multi-launch retained (R5 showed in-kernel agent-scope barriers cost 266us).

constexpr int Bsz = 128, Tn = 256, In = 256, Hn = 1024, Cn = 10;
constexpr float LR = 0.001f;

__global__ __launch_bounds__(256) void k_transpose(const float* __restrict__ W,
                                                   float* __restrict__ WT) {
  __shared__ float tile[32][33];
  const int bx = blockIdx.x * 32, by = blockIdx.y * 32;
  const int tx = threadIdx.x & 31, ty = threadIdx.x >> 5;
#pragma unroll
  for (int dy = 0; dy < 32; dy += 8)
    tile[ty + dy][tx] = W[(size_t)(by + ty + dy) * Hn + bx + tx];
  __syncthreads();
#pragma unroll
  for (int dy = 0; dy < 32; dy += 8)
    WT[(size_t)(bx + ty + dy) * Hn + by + tx] = tile[tx][ty + dy];
}

__global__ __launch_bounds__(256) void k_init(float* __restrict__ out,
                                              const float* __restrict__ fc_b,
                                              float* __restrict__ h_cur,
                                              const float* __restrict__ hidden) {
  const int i = blockIdx.x * blockDim.x + threadIdx.x;
  if (i < Bsz * Tn * Cn) out[i] = fc_b[i % Cn];
  if (i < Bsz * Hn) h_cur[i] = hidden[i];
}

__device__ __forceinline__ void fma4(float4& a, float s, const float4& w) {
  a.x = fmaf(s, w.x, a.x);
  a.y = fmaf(s, w.y, a.y);
  a.z = fmaf(s, w.z, a.z);
  a.w = fmaf(s, w.w, a.w);
}

__device__ __forceinline__ float4 shfl4(float4 v, int m) {
  v.x = __shfl_xor(v.x, m, 64);
  v.y = __shfl_xor(v.y, m, 64);
  v.z = __shfl_xor(v.z, m, 64);
  v.w = __shfl_xor(v.w, m, 64);
  return v;
}

__device__ __forceinline__ float4 add4(float4 a, float4 b) {
  return make_float4(a.x + b.x, a.y + b.y, a.z + b.z, a.w + b.w);
}

// XW[t][b][n] = sum_k X[b][t][k]*Wx[k][n] + bias[n].
__global__ __launch_bounds__(256) void k_xw(const float* __restrict__ X,
                                            const float* __restrict__ Wx,
                                            const float* __restrict__ bias,
                                            float* __restrict__ xw) {
  const int nt = blockIdx.x & 15, mt = blockIdx.x >> 4;
  const int t = mt >> 1, b0 = (mt & 1) * 64;
  const int cl = threadIdx.x & 15, rg = threadIdx.x >> 4;
  const int col = nt * 64 + cl * 4;
  const int row = b0 + rg * 4;
  float4 acc0 = {0, 0, 0, 0}, acc1 = {0, 0, 0, 0}, acc2 = {0, 0, 0, 0},
         acc3 = {0, 0, 0, 0};
  const size_t xstride = (size_t)Tn * In;
  const float* xp = X + ((size_t)row * Tn + t) * In;
  const float* wp = Wx + col;
#pragma unroll 2
  for (int k = 0; k < In; k += 4) {
    const float4 x0 = *(const float4*)(xp + k);
    const float4 x1 = *(const float4*)(xp + xstride + k);
    const float4 x2 = *(const float4*)(xp + 2 * xstride + k);
    const float4 x3 = *(const float4*)(xp + 3 * xstride + k);
    const float4 w0 = *(const float4*)(wp + (size_t)k * Hn);
    const float4 w1 = *(const float4*)(wp + (size_t)(k + 1) * Hn);
    const float4 w2 = *(const float4*)(wp + (size_t)(k + 2) * Hn);
    const float4 w3 = *(const float4*)(wp + (size_t)(k + 3) * Hn);
    fma4(acc0, x0.x, w0); fma4(acc0, x0.y, w1); fma4(acc0, x0.z, w2); fma4(acc0, x0.w, w3);
    fma4(acc1, x1.x, w0); fma4(acc1, x1.y, w1); fma4(acc1, x1.z, w2); fma4(acc1, x1.w, w3);
    fma4(acc2, x2.x, w0); fma4(acc2, x2.y, w1); fma4(acc2, x2.z, w2); fma4(acc2, x2.w, w3);
    fma4(acc3, x3.x, w0); fma4(acc3, x3.y, w1); fma4(acc3, x3.z, w2); fma4(acc3, x3.w, w3);
  }
  const float4 b4 = *(const float4*)(bias + col);
  float4 o[4] = {acc0, acc1, acc2, acc3};
#pragma unroll
  for (int i = 0; i < 4; i++) {
    float4 v = o[i];
    v.x += b4.x; v.y += b4.y; v.z += b4.z; v.w += b4.w;
    *(float4*)(xw + ((size_t)t * Bsz + row + i) * Hn + col) = v;
  }
}

// 8-rows x 16-cols x K=1024 panel GEMM; thread = c4(4) x kk(64). Rows read
// straight from global (L2-hot; 4 c4-lanes share each address -> broadcast).
__device__ __forceinline__ void gemm8g(const float* __restrict__ rows,
                                       const float* __restrict__ W, int kk,
                                       int col, float4 acc[8]) {
#pragma unroll
  for (int q = 0; q < 4; q++) {
    const int k = 4 * kk + 256 * q;
    const float* Wp = W + (size_t)k * Hn + col;
    const float4 w0 = *(const float4*)(Wp);
    const float4 w1 = *(const float4*)(Wp + Hn);
    const float4 w2 = *(const float4*)(Wp + 2 * Hn);
    const float4 w3 = *(const float4*)(Wp + 3 * Hn);
#pragma unroll
    for (int r = 0; r < 8; r++) {
      const float4 h4 = *(const float4*)(rows + (size_t)r * Hn + k);
      fma4(acc[r], h4.x, w0);
      fma4(acc[r], h4.y, w1);
      fma4(acc[r], h4.z, w2);
      fma4(acc[r], h4.w, w3);
    }
  }
}

// Value-splitting reduce over ks lane bits 2..5 (validated in R5): 30 shfl.
// Lane ends owning float2 at (r_own, 4*c4 + 2*u4); writes part[wv].
__device__ __forceinline__ void reduce_vs(float4 acc[8], int c4, int ksw,
                                          int wv, float (*part)[8][16]) {
  const bool u1 = ksw & 1;
#pragma unroll
  for (int i = 0; i < 4; i++) {
    const float4 snd = u1 ? acc[i] : acc[i + 4];
    const float4 kp = u1 ? acc[i + 4] : acc[i];
    acc[i] = add4(kp, shfl4(snd, 4));
  }
  const bool u2 = ksw & 2;
#pragma unroll
  for (int i = 0; i < 2; i++) {
    const float4 snd = u2 ? acc[i] : acc[i + 2];
    const float4 kp = u2 ? acc[i + 2] : acc[i];
    acc[i] = add4(kp, shfl4(snd, 8));
  }
  const bool u3 = ksw & 4;
  {
    const float4 snd = u3 ? acc[0] : acc[1];
    const float4 kp = u3 ? acc[1] : acc[0];
    acc[0] = add4(kp, shfl4(snd, 16));
  }
  const bool u4 = ksw & 8;
  float sx = u4 ? acc[0].x : acc[0].z;
  float sy = u4 ? acc[0].y : acc[0].w;
  const float kx = u4 ? acc[0].z : acc[0].x;
  const float ky = u4 ? acc[0].w : acc[0].y;
  sx = __shfl_xor(sx, 32, 64);
  sy = __shfl_xor(sy, 32, 64);
  const int r_own = ((ksw & 1) << 2) | (ksw & 2) | ((ksw >> 2) & 1);
  const int c_own = 4 * c4 + (u4 ? 2 : 0);
  *(float2*)&part[wv][r_own][c_own] = make_float2(kx + sx, ky + sy);
}

// grid 1024 = rt(16, 8 rows) x ct(64, 16 cols); thread = c4(4) x kk(64).
template <int PRE>
__global__ __launch_bounds__(256, 4) void k_phase1(
    const float* __restrict__ h, const float* __restrict__ X,
    const float* __restrict__ Wh, const float* __restrict__ Wx,
    const float* __restrict__ bias, const float* __restrict__ alpha,
    const float* __restrict__ xw, float* __restrict__ v_out, int t) {
  __shared__ float part[4][8][16];
  const int ct = blockIdx.x & 63, rt = blockIdx.x >> 6;
  const int c0 = ct * 16, r0 = rt * 8;
  const int tid = threadIdx.x;
  const int c4 = tid & 3, kk = tid >> 2;
  const int col = c0 + 4 * c4;
  const int wv = tid >> 6, ksw = (tid & 63) >> 2;
  const float* hbase = h + (size_t)r0 * Hn;

  float4 acc[8];
#pragma unroll
  for (int r = 0; r < 8; r++) acc[r] = {0.f, 0.f, 0.f, 0.f};
  gemm8g(hbase, Wh, kk, col, acc);
  if (!PRE) {  // x@Wx inline: thread kk owns Wx row-quad 4kk (I=256=64*4)
    const int kx = 4 * kk;
    const float* Wp = Wx + (size_t)kx * Hn + col;
    const float4 w0 = *(const float4*)(Wp);
    const float4 w1 = *(const float4*)(Wp + Hn);
    const float4 w2 = *(const float4*)(Wp + 2 * Hn);
    const float4 w3 = *(const float4*)(Wp + 3 * Hn);
#pragma unroll
    for (int r = 0; r < 8; r++) {
      const float4 x4 =
          *(const float4*)(X + ((size_t)(r0 + r) * Tn + t) * In + kx);
      fma4(acc[r], x4.x, w0);
      fma4(acc[r], x4.y, w1);
      fma4(acc[r], x4.z, w2);
      fma4(acc[r], x4.w, w3);
    }
  }
  reduce_vs(acc, c4, ksw, wv, part);
  __syncthreads();
  if (tid < 128) {
    const int r = tid >> 4, c = tid & 15;
    const float u =
        part[0][r][c] + part[1][r][c] + part[2][r][c] + part[3][r][c];
    const float a1 =
        PRE ? xw[((size_t)t * Bsz + r0 + r) * Hn + c0 + c] : bias[c0 + c];
    const float av = alpha[0];
    const float hv = hbase[(size_t)r * Hn + c0 + c];
    v_out[(size_t)(r0 + r) * Hn + c0 + c] = av * hv - fmaxf(u + a1, 0.f);
  }
}

__global__ __launch_bounds__(256, 4) void k_phase2(
    float* __restrict__ h, const float* __restrict__ v_in,
    const float* __restrict__ WT, const float* __restrict__ alpha,
    const float* __restrict__ fc_w, float* __restrict__ out,
    float* __restrict__ hfin, int t, int last) {
  __shared__ float part[4][8][16];
  __shared__ float hn_s[8][16];
  const int ct = blockIdx.x & 63, rt = blockIdx.x >> 6;
  const int c0 = ct * 16, r0 = rt * 8;
  const int tid = threadIdx.x;
  const int c4 = tid & 3, kk = tid >> 2;
  const int col = c0 + 4 * c4;
  const int wv = tid >> 6, ksw = (tid & 63) >> 2;
  const float* vbase = v_in + (size_t)r0 * Hn;

  float4 acc[8];
#pragma unroll
  for (int r = 0; r < 8; r++) acc[r] = {0.f, 0.f, 0.f, 0.f};
  gemm8g(vbase, WT, kk, col, acc);
  reduce_vs(acc, c4, ksw, wv, part);
  __syncthreads();
  if (tid < 128) {
    const int r = tid >> 4, c = tid & 15;
    const float u =
        part[0][r][c] + part[1][r][c] + part[2][r][c] + part[3][r][c];
    const float av = alpha[0];
    const size_t hoff = (size_t)(r0 + r) * Hn + c0 + c;
    const float vv = vbase[(size_t)r * Hn + c0 + c];
    const float hv = h[hoff];
    // phi = a*h - v; grad = a*v - (phi>0)*u; hn = h - LR*grad
    const float hn = hv - LR * (av * vv - ((av * hv - vv) > 0.f ? u : 0.f));
    h[hoff] = hn;
    if (last) hfin[hoff] = hn;
    hn_s[r][c] = hn;
  }
  __syncthreads();
  if (tid < 80) {  // FC partial over this block's 16 cols -> 80 atomics
    const int rr = tid / 10, c = tid % 10;
    float s = 0.f;
#pragma unroll
    for (int jj = 0; jj < 16; jj++)
      s += hn_s[rr][jj] * fc_w[(size_t)(c0 + jj) * Cn + c];
    atomicAdd(&out[((size_t)(r0 + rr) * Tn + t) * Cn + c], s);
  }
}

extern "C" void kernel_launch(void* const* d_in, const int* in_sizes, int n_in,
                              void* d_out, int out_size, void* d_ws, size_t ws_size,
                              hipStream_t stream) {
  const float* X      = (const float*)d_in[0];
  const float* hidden = (const float*)d_in[1];
  const float* alpha  = (const float*)d_in[2];
  const float* bias   = (const float*)d_in[3];
  const float* Wh     = (const float*)d_in[4];
  const float* Wx     = (const float*)d_in[5];
  const float* fc_w   = (const float*)d_in[6];
  const float* fc_b   = (const float*)d_in[7];
  float* out  = (float*)d_out;
  float* hfin = out + (size_t)Bsz * Tn * Cn;

  char* ws = (char*)d_ws;
  float* WhT   = (float*)ws;                        // 4 MB
  float* h_cur = WhT + (size_t)Hn * Hn;
  float* v_buf = h_cur + (size_t)Bsz * Hn;
  float* XW    = v_buf + (size_t)Bsz * Hn;          // 134 MB, [t][b][n]
  const size_t need =
      ((size_t)Hn * Hn + 2 * (size_t)Bsz * Hn + (size_t)Bsz * Tn * Hn) *
      sizeof(float);
  const bool pre = ws_size >= need;

  k_transpose<<<dim3(32, 32), 256, 0, stream>>>(Wh, WhT);
  k_init<<<(Bsz * Tn * Cn + 255) / 256, 256, 0, stream>>>(out, fc_b, h_cur,
                                                          hidden);
  if (pre) k_xw<<<8192, 256, 0, stream>>>(X, Wx, bias, XW);
  for (int t = 0; t < Tn; t++) {
    if (pre)
      k_phase1<1><<<1024, 256, 0, stream>>>(h_cur, X, Wh, Wx, bias, alpha, XW,
                                            v_buf, t);
    else
      k_phase1<0><<<1024, 256, 0, stream>>>(h_cur, X, Wh, Wx, bias, alpha, XW,
                                            v_buf, t);
    k_phase2<<<1024, 256, 0, stream>>>(h_cur, v_buf, WhT, alpha, fc_w, out,
                                       hfin, t, t == Tn - 1);
  }
}